// Round 7
// baseline (434.361 us; speedup 1.0000x reference)
//
#include <hip/hip_runtime.h>

// ---------------------------------------------------------------------------
// RelativeAttention: L=2048, B=2, HID=1024, H=16, DH=64, P=50
//   q,k,v = x @ W^T + b            (bf16 MFMA GEMM, fp32 accumulate)
//   attn  = softmax((QK^T + Sr_gather)/8),  Sr[q,j] = Q[q]·rel_k[j]
//   out_h = attn@V + T@rel_v,      T[q,j] = sum of p over bucket j
//   out   = out_h @ Wo^T + bo      (written [L,B,HID])
// R14 = R13 (barrier-free swapped-QK, PASSED @255us) + K register
//   double-buffer restored (R13's regression vs R12 was the missing K
//   prefetch: global K fed the QK MFMA with raw L2 latency in the serial
//   chain every iteration). Per iter: issue V(i) loads, then K(i+1) into the
//   alternate register set, compute QK with resident K(i). V older in vmcnt
//   queue than K-prefetch -> PV's wait doesn't drain the prefetch.
//   Fence discipline unchanged from R13 (lgkmcnt(0)+sched_barrier(0), rule 18)
//   -- this is what R8/R9 lacked and why they NaN'd.
// ---------------------------------------------------------------------------

#define LSEQ 2048
#define HIDDIM 1024
#define NH 16
#define DHD 64
#define NREL 101
#define PMAX 50
#define SCL 0.18033688011112042f   // 0.125 * log2(e)

typedef __attribute__((ext_vector_type(8))) __bf16 bf16x8;
typedef __attribute__((ext_vector_type(4))) float f32x4;

#define MFMA(A, B, C) __builtin_amdgcn_mfma_f32_16x16x32_bf16(A, B, C, 0, 0, 0)
#define LDS_FENCE() do { \
    asm volatile("s_waitcnt lgkmcnt(0)" ::: "memory"); \
    __builtin_amdgcn_sched_barrier(0); \
  } while (0)

__device__ __forceinline__ unsigned short f2bf(float f) {
  unsigned int u = __builtin_bit_cast(unsigned int, f);
  u += 0x7fffu + ((u >> 16) & 1u);   // RNE
  return (unsigned short)(u >> 16);
}
__device__ __forceinline__ float bflo(unsigned int u) { return __builtin_bit_cast(float, u << 16); }

__device__ __forceinline__ unsigned cvtpk(float lo, float hi) {
  unsigned r;
  asm("v_cvt_pk_bf16_f32 %0, %1, %2" : "=v"(r) : "v"(lo), "v"(hi));
  return r;
}
__device__ __forceinline__ float pklo(unsigned pk) { return __builtin_bit_cast(float, pk << 16); }
__device__ __forceinline__ float pkhi(unsigned pk) { return __builtin_bit_cast(float, pk & 0xffff0000u); }

__device__ __forceinline__ uint4 pack8(float4 f0, float4 f1) {
  uint4 o;
  o.x = (unsigned)f2bf(f0.x) | ((unsigned)f2bf(f0.y) << 16);
  o.y = (unsigned)f2bf(f0.z) | ((unsigned)f2bf(f0.w) << 16);
  o.z = (unsigned)f2bf(f1.x) | ((unsigned)f2bf(f1.y) << 16);
  o.w = (unsigned)f2bf(f1.z) | ((unsigned)f2bf(f1.w) << 16);
  return o;
}

// async global->LDS, 16B per lane, wave-uniform LDS base + lane*16
__device__ __forceinline__ void gload16(const unsigned short* g, unsigned short* l) {
  __builtin_amdgcn_global_load_lds(
      (const __attribute__((address_space(1))) unsigned int*)g,
      (__attribute__((address_space(3))) unsigned int*)l, 16, 0, 0);
}

// 4 weights fp32 [1024,1024] -> bf16, one dispatch. 8 elems/thread.
__global__ void cast_w4(const float* __restrict__ s0, const float* __restrict__ s1,
                        const float* __restrict__ s2, const float* __restrict__ s3,
                        unsigned short* __restrict__ dst) {
  const int e = (blockIdx.x * 256 + threadIdx.x) * 8;
  const int g = e >> 20;
  const float* s = (g == 0) ? s0 : (g == 1) ? s1 : (g == 2) ? s2 : s3;
  const int o = e & 0xFFFFF;
  const float4 f0 = *(const float4*)(s + o);
  const float4 f1 = *(const float4*)(s + o + 4);
  *(uint4*)(dst + e) = pack8(f0, f1);
}

// query/key/value [L,B,HID] fp32 -> bf16 [4096,1024] (row m = b*L+l), one dispatch
__global__ void cast_x3(const float* __restrict__ q, const float* __restrict__ k,
                        const float* __restrict__ v,
                        unsigned short* __restrict__ dq, unsigned short* __restrict__ dk,
                        unsigned short* __restrict__ dv) {
  const int gid = blockIdx.x * 256 + threadIdx.x;
  const int segi = gid >> 19;                   // 2^19 threads per input (4M elems / 8)
  const int e = (gid & 0x7FFFF) * 8;
  const float* s = (segi == 0) ? q : (segi == 1) ? k : v;
  unsigned short* dst = (segi == 0) ? dq : (segi == 1) ? dk : dv;
  const int m = e >> 10, kk = e & 1023;
  const int b = m >> 11, l = m & 2047;
  const float* sp = s + (size_t)((l << 1) + b) * HIDDIM + kk;
  const float4 f0 = *(const float4*)sp;
  const float4 f1 = *(const float4*)(sp + 4);
  *(uint4*)(dst + e) = pack8(f0, f1);
}

// rel_k fp32 [101][64] -> bf16 [112][64], rows 101..111 zeroed
__global__ void cast_rk_kernel(const float* __restrict__ src, unsigned short* __restrict__ dst) {
  const int e = blockIdx.x * 256 + threadIdx.x;
  if (e >= 112 * 64) return;
  dst[e] = (e < NREL * 64) ? f2bf(src[e]) : (unsigned short)0;
}

// rel_v fp32 [101][64] -> transposed bf16 [64][128]: RVb[d][j], j>=101 zero
__global__ void cast_rv_kernel(const float* __restrict__ src, unsigned short* __restrict__ dst) {
  const int e = blockIdx.x * 256 + threadIdx.x;
  if (e >= 64 * 128) return;
  const int d = e >> 7, j = e & 127;
  dst[e] = (j < NREL) ? f2bf(src[j * DHD + d]) : (unsigned short)0;
}

// ---------------------------------------------------------------------------
// Fused Q/K/V projection (verified R11). grid = 3*256; seg = bid>>8.
// ---------------------------------------------------------------------------
__global__ __launch_bounds__(256, 3) void gemm_qkv(
    const unsigned short* __restrict__ Xq, const unsigned short* __restrict__ Xk,
    const unsigned short* __restrict__ Xv, const unsigned short* __restrict__ Wcat,
    const float* __restrict__ bq, const float* __restrict__ bk, const float* __restrict__ bv,
    unsigned short* __restrict__ Qb, unsigned short* __restrict__ Kb,
    unsigned short* __restrict__ Vgt) {
  __shared__ __align__(16) unsigned short SH[17408];   // 34816 B (also Ct 128x136)
  unsigned short* LA = SH;           // [128][64] bf16, swizzled content
  unsigned short* LB = SH + 8192;

  const int tid = threadIdx.x;
  const int seg = blockIdx.x >> 8;
  const int t = blockIdx.x & 255;
  const int m0 = (t >> 3) * 128, n0 = (t & 7) * 128;

  const unsigned short* A = (seg == 0) ? Xq : (seg == 1) ? Xk : Xv;
  const unsigned short* W = Wcat + ((size_t)seg << 20);
  const float* bias = (seg == 0) ? bq : (seg == 1) ? bk : bv;

  const int lane = tid & 63, w = tid >> 6;
  const int c = lane & 15, quad = lane >> 4;

  const int srow = w * 32 + (lane >> 3);
  const int scol = ((lane & 7) ^ (lane >> 3)) << 3;    // elems
  const unsigned short* pA = A + (size_t)(m0 + srow) * 1024 + scol;
  const unsigned short* pW = W + (size_t)(n0 + srow) * 1024 + scol;
  unsigned short* lA = LA + w * 2048;
  unsigned short* lB = LB + w * 2048;

  const int wr = w >> 1, wc = w & 1;
  const int cx = (c & 7) << 3;                         // frag-read XOR (elems)

  f32x4 acc[4][4] = {};

  for (int k0 = 0; k0 < 1024; k0 += 64) {
#pragma unroll
    for (int i = 0; i < 4; i++) {
      gload16(pA + k0 + i * 8192, lA + i * 512);
      gload16(pW + k0 + i * 8192, lB + i * 512);
    }
    __syncthreads();   // drains vmcnt: staged data visible
#pragma unroll
    for (int ks = 0; ks < 2; ks++) {
      bf16x8 af[4], bfr[4];
#pragma unroll
      for (int f = 0; f < 4; f++) {
        af[f]  = *(const bf16x8*)&LA[(wr * 64 + f * 16 + c) * 64 + ((ks * 32 + quad * 8) ^ cx)];
        bfr[f] = *(const bf16x8*)&LB[(wc * 64 + f * 16 + c) * 64 + ((ks * 32 + quad * 8) ^ cx)];
      }
#pragma unroll
      for (int i = 0; i < 4; i++)
#pragma unroll
        for (int j = 0; j < 4; j++)
          acc[i][j] = MFMA(af[i], bfr[j], acc[i][j]);
    }
    __syncthreads();
  }

  const int b = m0 >> 11, l0 = m0 & 2047;
  const int h0 = n0 >> 6;
  if (seg < 2) {
    unsigned short* out = seg ? Kb : Qb;
#pragma unroll
    for (int i = 0; i < 4; i++)
#pragma unroll
      for (int j = 0; j < 4; j++) {
        const int nl = wc * 64 + j * 16 + c;            // C/D col = lane&15
        const float bv_ = bias[n0 + nl];
        const int h = h0 + (nl >> 6), d = nl & 63;
#pragma unroll
        for (int r = 0; r < 4; r++) {                   // C/D row = quad*4+r
          const int l = l0 + wr * 64 + i * 16 + quad * 4 + r;
          out[((size_t)((b * NH + h) * LSEQ + l) << 6) + d] = f2bf(acc[i][j][r] + bv_);
        }
      }
  } else {
    unsigned short* Ct = SH;
#pragma unroll
    for (int i = 0; i < 4; i++)
#pragma unroll
      for (int j = 0; j < 4; j++) {
        const int nl = wc * 64 + j * 16 + c;
        const float bv_ = bias[n0 + nl];
#pragma unroll
        for (int r = 0; r < 4; r++) {
          const int ml = wr * 64 + i * 16 + quad * 4 + r;
          Ct[nl * 136 + ml] = f2bf(acc[i][j][r] + bv_);
        }
      }
    __syncthreads();
    const int dr = tid >> 1, lc = (tid & 1) * 64;
    const int h = h0 + (dr >> 6), dd = dr & 63;
    unsigned short* dst = Vgt + ((size_t)((b * NH + h) * 64 + dd)) * LSEQ + l0 + lc;
    const unsigned short* src = Ct + dr * 136 + lc;
#pragma unroll
    for (int u = 0; u < 8; u++)
      *(uint4*)(dst + u * 8) = *(const uint4*)(src + u * 8);
  }
}

// C[m,n] = sum_k A[m,k]*W[n,k] + bias[n]; MODE 1: fp32 [L,B,HID] (output GEMM)
template <int MODE>
__global__ __launch_bounds__(256, 4) void gemm64(
    const unsigned short* __restrict__ A,   // [4096,1024] bf16
    const unsigned short* __restrict__ W,   // [1024,1024] bf16
    const float* __restrict__ bias,
    float* __restrict__ outF,
    unsigned short* __restrict__ outB) {
  constexpr int K = 1024;
  __shared__ unsigned short As[64 * 72];
  __shared__ unsigned short Bs[64 * 72];
  const int tid = threadIdx.x;
  const int tm = blockIdx.x >> 4, tn = blockIdx.x & 15;
  const int m0 = tm * 64, n0 = tn * 64;
  const int lane = tid & 63, wave = tid >> 6;
  const int wm = (wave >> 1) * 32, wn = (wave & 1) * 32;
  const int qr = lane & 15, quad = lane >> 4;
  const int sr = tid >> 3, sc = (tid & 7) * 8;
  f32x4 acc[2][2] = {};
  for (int k0 = 0; k0 < K; k0 += 64) {
    *(uint4*)&As[sr * 72 + sc]        = *(const uint4*)&A[(size_t)(m0 + sr) * K + k0 + sc];
    *(uint4*)&As[(sr + 32) * 72 + sc] = *(const uint4*)&A[(size_t)(m0 + sr + 32) * K + k0 + sc];
    *(uint4*)&Bs[sr * 72 + sc]        = *(const uint4*)&W[(size_t)(n0 + sr) * K + k0 + sc];
    *(uint4*)&Bs[(sr + 32) * 72 + sc] = *(const uint4*)&W[(size_t)(n0 + sr + 32) * K + k0 + sc];
    __syncthreads();
#pragma unroll
    for (int ks = 0; ks < 64; ks += 32) {
      bf16x8 a0 = *(const bf16x8*)&As[(wm + qr) * 72 + ks + quad * 8];
      bf16x8 a1 = *(const bf16x8*)&As[(wm + 16 + qr) * 72 + ks + quad * 8];
      bf16x8 b0 = *(const bf16x8*)&Bs[(wn + qr) * 72 + ks + quad * 8];
      bf16x8 b1 = *(const bf16x8*)&Bs[(wn + 16 + qr) * 72 + ks + quad * 8];
      acc[0][0] = MFMA(a0, b0, acc[0][0]);
      acc[0][1] = MFMA(a0, b1, acc[0][1]);
      acc[1][0] = MFMA(a1, b0, acc[1][0]);
      acc[1][1] = MFMA(a1, b1, acc[1][1]);
    }
    __syncthreads();
  }
#pragma unroll
  for (int i = 0; i < 2; i++)
#pragma unroll
    for (int j = 0; j < 2; j++) {
      const int n = n0 + wn + 16 * j + qr;      // C/D: col = lane&15
      const float bv = bias[n];
#pragma unroll
      for (int rr = 0; rr < 4; rr++) {
        const int m = m0 + wm + 16 * i + quad * 4 + rr;  // row = quad*4+reg
        const float v = acc[i][j][rr] + bv;
        const int b = m >> 11, l = m & 2047;
        if (MODE == 1) {
          outF[(size_t)((l << 1) + b) * HIDDIM + n] = v;
        }
      }
    }
}

// ---------------------------------------------------------------------------
// Barrier-free flash attention (R13 numerics, PASSED) + K register
// double-buffer. Block = 256 thr = 4 independent waves; each wave owns 16
// q-rows of one (b,h). Swapped QK: lane(quad,c) holds
// P[k=k0+16kt+quad*4+r][q=c]. V issued first (older vmcnt), K(i+1) prefetch
// second; QK consumes resident K(i) registers. NO __syncthreads.
// LDS per block (u16): Ptw 4x[16][40] | Tb 4x[16][104] | SrS 4x[16][104]
//   = 15872 u16 = 31744 B.
// ---------------------------------------------------------------------------
#define KT 32

#define ATT_BODY(KC0, KC1, KC2, KC3, KN0, KN1, KN2, KN3, IT)                    \
  {                                                                             \
    const int k0_ = (IT) * KT;                                                  \
    const int kn_ = (((IT) < 63) ? ((IT) + 1) : 63) * KT;                       \
    /* V for current tile: issued first (older in vmcnt queue) */               \
    bf16x8 vf[4];                                                               \
    _Pragma("unroll")                                                           \
    for (int t = 0; t < 4; t++)                                                 \
      vf[t] = *(const bf16x8*)&Vp[(size_t)(t * 16 + c) * LSEQ + k0_ + quad * 8];\
    /* prefetch next K tile into the alternate register set */                  \
    KN0 = *(const bf16x8*)&Kp[(size_t)(kn_ + c) * DHD + quad * 8];              \
    KN1 = *(const bf16x8*)&Kp[(size_t)(kn_ + c) * DHD + 32 + quad * 8];         \
    KN2 = *(const bf16x8*)&Kp[(size_t)(kn_ + 16 + c) * DHD + quad * 8];         \
    KN3 = *(const bf16x8*)&Kp[(size_t)(kn_ + 16 + c) * DHD + 32 + quad * 8];    \
    /* QK with resident K registers */                                          \
    f32x4 s0 = {}, s1 = {};                                                     \
    s0 = MFMA(KC0, aq0, s0);                                                    \
    s0 = MFMA(KC1, aq1, s0);                                                    \
    s1 = MFMA(KC2, aq0, s1);                                                    \
    s1 = MFMA(KC3, aq1, s1);                                                    \
    const int mode = (k0_ + KT - 1 <= qrow_w - 50) ? 0 : (k0_ >= qrow_w + 65) ? 2 : 1; \
    unsigned pkA0, pkA1, pkB0, pkB1;                                            \
    if (mode != 1) {                                                            \
      const float srv = (mode == 0) ? srvlo : srvhi;                            \
      const float e0 = exp2f((s0[0] + srv) * SCL);                              \
      const float e1 = exp2f((s0[1] + srv) * SCL);                              \
      const float e2 = exp2f((s0[2] + srv) * SCL);                              \
      const float e3 = exp2f((s0[3] + srv) * SCL);                              \
      const float e4 = exp2f((s1[0] + srv) * SCL);                              \
      const float e5 = exp2f((s1[1] + srv) * SCL);                              \
      const float e6 = exp2f((s1[2] + srv) * SCL);                              \
      const float e7 = exp2f((s1[3] + srv) * SCL);                              \
      pkA0 = cvtpk(e0, e1); pkA1 = cvtpk(e2, e3);                               \
      pkB0 = cvtpk(e4, e5); pkB1 = cvtpk(e6, e7);                               \
      const float sq = ((pklo(pkA0) + pkhi(pkA0)) + (pklo(pkA1) + pkhi(pkA1)))  \
                     + ((pklo(pkB0) + pkhi(pkB0)) + (pklo(pkB1) + pkhi(pkB1))); \
      if (mode == 0) lows += sq; else highs += sq;                              \
    } else {                                                                    \
      const int kb0 = k0_ + quad * 4 - (qrow_w + c) + 50;                       \
      float ee[8]; int jj[8];                                                   \
      _Pragma("unroll")                                                         \
      for (int r = 0; r < 4; r++) {                                             \
        int j0 = kb0 + r;       j0 = j0 < 0 ? 0 : (j0 > 100 ? 100 : j0);        \
        int j1 = kb0 + 16 + r;  j1 = j1 < 0 ? 0 : (j1 > 100 ? 100 : j1);        \
        jj[r] = j0; jj[4 + r] = j1;                                             \
        const float sv0 = bflo((unsigned)SrS[c * 104 + j0]);                    \
        const float sv1 = bflo((unsigned)SrS[c * 104 + j1]);                    \
        ee[r]     = exp2f((s0[r] + sv0) * SCL);                                 \
        ee[4 + r] = exp2f((s1[r] + sv1) * SCL);                                 \
      }                                                                         \
      pkA0 = cvtpk(ee[0], ee[1]); pkA1 = cvtpk(ee[2], ee[3]);                   \
      pkB0 = cvtpk(ee[4], ee[5]); pkB1 = cvtpk(ee[6], ee[7]);                   \
      const unsigned pks[4] = {pkA0, pkA1, pkB0, pkB1};                         \
      _Pragma("unroll")                                                         \
      for (int i = 0; i < 4; i++) {                                             \
        const unsigned pk = pks[i];                                             \
        const float plo = pklo(pk), phi = pkhi(pk);                             \
        const int jl = jj[2 * i], jh = jj[2 * i + 1];                           \
        if (jl == 0) lows += plo;                                               \
        else if (jl == 100) highs += plo;                                       \
        else { mids += plo; Tb[c * 104 + jl] = (unsigned short)pk; }            \
        if (jh == 0) lows += phi;                                               \
        else if (jh == 100) highs += phi;                                       \
        else { mids += phi; Tb[c * 104 + jh] = (unsigned short)(pk >> 16); }    \
      }                                                                         \
    }                                                                           \
    /* P round-trip: 2x b64 write + 1x b128 read (pitch 40) */                  \
    uint2 w0; w0.x = pkA0; w0.y = pkA1;                                         \
    uint2 w1; w1.x = pkB0; w1.y = pkB1;                                         \
    *(uint2*)&Ptw[c * 40 + quad * 4] = w0;                                      \
    *(uint2*)&Ptw[c * 40 + 16 + quad * 4] = w1;                                 \
    LDS_FENCE();                                                                \
    const bf16x8 ap = *(const bf16x8*)&Ptw[c * 40 + quad * 8];                  \
    _Pragma("unroll")                                                           \
    for (int t = 0; t < 4; t++)                                                 \
      Od[t] = MFMA(ap, vf[t], Od[t]);                                           \
  }

__global__ __launch_bounds__(256, 4) void attn_mfma(
    const unsigned short* __restrict__ Qb,   // [32][2048][64] bf16
    const unsigned short* __restrict__ Kb,   // [32][2048][64] bf16
    const unsigned short* __restrict__ Vgt,  // [32][64][2048] bf16 (V^T)
    const unsigned short* __restrict__ RKb,  // [112][64] bf16, zero-padded
    const unsigned short* __restrict__ RVb,  // [64][128] bf16 (rel_v^T), zero-padded
    unsigned short* __restrict__ outB) {     // [B*L][1024] bf16
  __shared__ __align__(16) unsigned short SH[15872];

  const int tid = threadIdx.x;
  const int xcd = blockIdx.x & 7, slot = blockIdx.x >> 3;
  const int bh = (slot >> 5) * 8 + xcd;
  const int q0 = (slot & 31) * 64;

  const int lane = tid & 63, wq = tid >> 6;
  const int c = lane & 15, quad = lane >> 4;
  unsigned short* Ptw = SH + wq * 640;           // [16][40] per wave
  unsigned short* Tb  = SH + 2560 + wq * 1664;   // [16][104] per wave
  unsigned short* SrS = SH + 9216 + wq * 1664;   // [16][104] per wave

  const size_t base = (size_t)bh * (LSEQ * DHD);
  const unsigned short* Qp = Qb + base;
  const unsigned short* Kp = Kb + base;
  const unsigned short* Vp = Vgt + base;

  const int qrow_w = q0 + wq * 16;    // wave's first global q

  // zero OWN wave's Tb only (16x104 u16 = 208 uint4): no cross-wave coupling
  {
    uint4 z = {0u, 0u, 0u, 0u};
    uint4* tz = (uint4*)Tb;
#pragma unroll
    for (int i = 0; i < 3; i++) tz[lane + 64 * i] = z;
    if (lane < 16) tz[lane + 192] = z;
  }

  // Q fragments (B-operand: n = lane&15 -> own q-row, k = quad*8+e -> d)
  const bf16x8 aq0 = *(const bf16x8*)&Qp[(size_t)(qrow_w + c) * DHD + quad * 8];
  const bf16x8 aq1 = *(const bf16x8*)&Qp[(size_t)(qrow_w + c) * DHD + 32 + quad * 8];

  // Sr swapped: lane(quad,c) -> Sr[j = jt*16+quad*4+r][q = qrow_w+c],
  // stored row-per-q: SrS[c][j] via cvt_pk u32 pairs (RNE, == f2bf bits)
#pragma unroll
  for (int jt = 0; jt < 7; jt++) {
    const bf16x8 rk0 = *(const bf16x8*)&RKb[(jt * 16 + c) * DHD + quad * 8];
    const bf16x8 rk1 = *(const bf16x8*)&RKb[(jt * 16 + c) * DHD + 32 + quad * 8];
    f32x4 s4 = {};
    s4 = MFMA(rk0, aq0, s4);
    s4 = MFMA(rk1, aq1, s4);
    const int jb = jt * 16 + quad * 4;
    const unsigned p01 = cvtpk(s4[0], s4[1]);
    const unsigned p23 = cvtpk(s4[2], s4[3]);
    if (jb <= 102)     *(unsigned*)&SrS[c * 104 + jb] = p01;
    if (jb + 2 <= 102) *(unsigned*)&SrS[c * 104 + jb + 2] = p23;
  }
  LDS_FENCE();   // Tb zero + SrS writes complete (wave-internal cross-lane)

  const float srvlo = bflo((unsigned)SrS[c * 104 + 0]);
  const float srvhi = bflo((unsigned)SrS[c * 104 + 100]);

  float lows = 0.f, highs = 0.f, mids = 0.f;
  f32x4 Od[4] = {};

  // preload K tile 0 into the x register set
  bf16x8 kx0 = *(const bf16x8*)&Kp[(size_t)(0 + c) * DHD + quad * 8];
  bf16x8 kx1 = *(const bf16x8*)&Kp[(size_t)(0 + c) * DHD + 32 + quad * 8];
  bf16x8 kx2 = *(const bf16x8*)&Kp[(size_t)(16 + c) * DHD + quad * 8];
  bf16x8 kx3 = *(const bf16x8*)&Kp[(size_t)(16 + c) * DHD + 32 + quad * 8];
  bf16x8 ky0, ky1, ky2, ky3;

  for (int it = 0; it < 64; it += 2) {
    ATT_BODY(kx0, kx1, kx2, kx3, ky0, ky1, ky2, ky3, it)
    ATT_BODY(ky0, ky1, ky2, ky3, kx0, kx1, kx2, kx3, it + 1)
  }

  // reduce per-q partials across the 4 quad-lanes holding the same c
#pragma unroll
  for (int m = 16; m < 64; m <<= 1) {
    lows  += __shfl_xor(lows,  m, 64);
    highs += __shfl_xor(highs, m, 64);
    mids  += __shfl_xor(mids,  m, 64);
  }
  const float rsum = (lows + highs) + mids;
  if (lane < 16) {
    Tb[c * 104 + 0]   = f2bf(lows);    // bucket 0 never stored in loop
    Tb[c * 104 + 100] = f2bf(highs);   // bucket 100 likewise
  }
  LDS_FENCE();   // Tb finalize visible (wave-internal)

  // w2: O += T @ rel_v via MFMA; A-frag = b128 from own q-row (cols j>=101
  // are zero; kc==3 reads only quad==0 — cols 96..103 — rest contribute 0)
#pragma unroll
  for (int kc = 0; kc < 4; kc++) {
    uint4 zz = {0u, 0u, 0u, 0u};
    bf16x8 at = __builtin_bit_cast(bf16x8, zz);
    if (kc < 3 || quad == 0) at = *(const bf16x8*)&Tb[c * 104 + kc * 32 + quad * 8];
#pragma unroll
    for (int t = 0; t < 4; t++) {
      const bf16x8 bv = *(const bf16x8*)&RVb[(t * 16 + c) * 128 + kc * 32 + quad * 8];
      Od[t] = MFMA(at, bv, Od[t]);
    }
  }

  const int b = bh >> 4, h = bh & 15;
#pragma unroll
  for (int r = 0; r < 4; r++) {
    const float rs = __shfl(rsum, quad * 4 + r, 64);  // lane (quad*4+r) holds q-row quad*4+r
    const float inv = 1.f / rs;
    const int qg = qrow_w + quad * 4 + r;             // Od row = quad*4+r
    unsigned short* op = outB + (size_t)(b * LSEQ + qg) * HIDDIM + h * DHD + c;
#pragma unroll
    for (int t = 0; t < 4; t++) op[t * 16] = f2bf(Od[t][r] * inv);
  }
}

extern "C" void kernel_launch(void* const* d_in, const int* in_sizes, int n_in,
                              void* d_out, int out_size, void* d_ws, size_t ws_size,
                              hipStream_t stream) {
  const float* query = (const float*)d_in[0];
  const float* key   = (const float*)d_in[1];
  const float* value = (const float*)d_in[2];
  const float* Wq = (const float*)d_in[3];  const float* bq = (const float*)d_in[4];
  const float* Wk = (const float*)d_in[5];  const float* bk = (const float*)d_in[6];
  const float* Wv = (const float*)d_in[7];  const float* bv = (const float*)d_in[8];
  const float* Wo = (const float*)d_in[9];  const float* bo = (const float*)d_in[10];
  const float* relk = (const float*)d_in[11];
  const float* relv = (const float*)d_in[12];
  float* out = (float*)d_out;

  // 40 MB workspace layout
  char* w = (char*)d_ws;
  const size_t MB = 1ull << 20;
  unsigned short* Wcat = (unsigned short*)(w + 0 * MB);  // Wq,Wk,Wv,Wo at 0/2/4/6 MB
  unsigned short* Wob  = (unsigned short*)(w + 6 * MB);
  unsigned short* Xq   = (unsigned short*)(w + 8 * MB);  // 8 MB; reused as AOb
  unsigned short* Qb   = (unsigned short*)(w + 16 * MB); // [32][2048][64]
  unsigned short* Kb   = (unsigned short*)(w + 24 * MB);
  unsigned short* Vgt  = (unsigned short*)(w + 32 * MB); // [32][64][2048] (V^T)
  unsigned short* AOb  = Xq;
  unsigned short* RKb  = Wcat;                            // aliases Wq (dead post-QKV)
  unsigned short* RVb  = (unsigned short*)(w + 2 * MB);   // aliases Wk (dead post-QKV)
  // Xk/Xv scratch inside d_out (16 MB fp32, fully overwritten by final GEMM)
  unsigned short* Xk = (unsigned short*)out;
  unsigned short* Xv = (unsigned short*)out + (4u << 20);

  cast_w4<<<2048, 256, 0, stream>>>(Wq, Wk, Wv, Wo, Wcat);
  cast_x3<<<6144, 256, 0, stream>>>(query, key, value, Xq, Xk, Xv);
  gemm_qkv<<<768, 256, 0, stream>>>(Xq, Xk, Xv, Wcat, bq, bk, bv, Qb, Kb, Vgt);
  cast_rk_kernel<<<28, 256, 0, stream>>>(relk, RKb);   // after QKV gemm (aliases Wq)
  cast_rv_kernel<<<32, 256, 0, stream>>>(relv, RVb);   // after QKV gemm (aliases Wk)
  attn_mfma<<<1024, 256, 0, stream>>>(Qb, Kb, Vgt, RKb, RVb, AOb);
  gemm64<1><<<1024, 256, 0, stream>>>(AOb, Wob, bo, out, nullptr);
}

// Round 9
// 325.920 us; speedup vs baseline: 1.3327x; 1.3327x over previous
//
#include <hip/hip_runtime.h>

// ---------------------------------------------------------------------------
// RelativeAttention: L=2048, B=2, HID=1024, H=16, DH=64, P=50
//   q,k,v = x @ W^T + b            (bf16 MFMA GEMM, fp32 accumulate)
//   attn  = softmax((QK^T + Sr_gather)/8),  Sr[q,j] = Q[q]·rel_k[j]
//   out_h = attn@V + T@rel_v,      T[q,j] = sum of p over bucket j
//   out   = out_h @ Wo^T + bo      (written [L,B,HID])
// R16: barrier-free line RETIRED (R8/R9/R15 NaN; R13/R14 pass-but-slow).
//   - attn_mfma: R12 hybrid byte-for-byte (BEST passing attention, 154.5us:
//     R7 4-wave skeleton w/ K LDS dbuf + 1 barrier/iter, swapped-QK register
//     layout, cvt_pk softmax, Ptw pitch-40 round-trip w/ lgkmcnt fence).
//   - cast_rel: rel_k + rel_v merged into one dispatch (6 dispatches total).
//   - gemm_out: final GEMM upgraded to the PROVEN gemm_qkv 128^2-tile core
//     (global_load_lds w16 + XOR swizzle) with fp32 MODE1 epilogue.
//     Accumulation order identical to gemm64 -> bit-identical output.
// ---------------------------------------------------------------------------

#define LSEQ 2048
#define HIDDIM 1024
#define NH 16
#define DHD 64
#define NREL 101
#define PMAX 50
#define SCL 0.18033688011112042f   // 0.125 * log2(e)

typedef __attribute__((ext_vector_type(8))) __bf16 bf16x8;
typedef __attribute__((ext_vector_type(4))) float f32x4;

#define MFMA(A, B, C) __builtin_amdgcn_mfma_f32_16x16x32_bf16(A, B, C, 0, 0, 0)
#define LDS_FENCE() asm volatile("s_waitcnt lgkmcnt(0)" ::: "memory")

__device__ __forceinline__ unsigned short f2bf(float f) {
  unsigned int u = __builtin_bit_cast(unsigned int, f);
  u += 0x7fffu + ((u >> 16) & 1u);   // RNE
  return (unsigned short)(u >> 16);
}
__device__ __forceinline__ float bflo(unsigned int u) { return __builtin_bit_cast(float, u << 16); }

__device__ __forceinline__ unsigned cvtpk(float lo, float hi) {
  unsigned r;
  asm("v_cvt_pk_bf16_f32 %0, %1, %2" : "=v"(r) : "v"(lo), "v"(hi));
  return r;
}
__device__ __forceinline__ float pklo(unsigned pk) { return __builtin_bit_cast(float, pk << 16); }
__device__ __forceinline__ float pkhi(unsigned pk) { return __builtin_bit_cast(float, pk & 0xffff0000u); }

__device__ __forceinline__ uint4 pack8(float4 f0, float4 f1) {
  uint4 o;
  o.x = (unsigned)f2bf(f0.x) | ((unsigned)f2bf(f0.y) << 16);
  o.y = (unsigned)f2bf(f0.z) | ((unsigned)f2bf(f0.w) << 16);
  o.z = (unsigned)f2bf(f1.x) | ((unsigned)f2bf(f1.y) << 16);
  o.w = (unsigned)f2bf(f1.z) | ((unsigned)f2bf(f1.w) << 16);
  return o;
}

// async global->LDS, 16B per lane, wave-uniform LDS base + lane*16
__device__ __forceinline__ void gload16(const unsigned short* g, unsigned short* l) {
  __builtin_amdgcn_global_load_lds(
      (const __attribute__((address_space(1))) unsigned int*)g,
      (__attribute__((address_space(3))) unsigned int*)l, 16, 0, 0);
}

// 4 weights fp32 [1024,1024] -> bf16, one dispatch. 8 elems/thread.
__global__ void cast_w4(const float* __restrict__ s0, const float* __restrict__ s1,
                        const float* __restrict__ s2, const float* __restrict__ s3,
                        unsigned short* __restrict__ dst) {
  const int e = (blockIdx.x * 256 + threadIdx.x) * 8;
  const int g = e >> 20;
  const float* s = (g == 0) ? s0 : (g == 1) ? s1 : (g == 2) ? s2 : s3;
  const int o = e & 0xFFFFF;
  const float4 f0 = *(const float4*)(s + o);
  const float4 f1 = *(const float4*)(s + o + 4);
  *(uint4*)(dst + e) = pack8(f0, f1);
}

// query/key/value [L,B,HID] fp32 -> bf16 [4096,1024] (row m = b*L+l), one dispatch
__global__ void cast_x3(const float* __restrict__ q, const float* __restrict__ k,
                        const float* __restrict__ v,
                        unsigned short* __restrict__ dq, unsigned short* __restrict__ dk,
                        unsigned short* __restrict__ dv) {
  const int gid = blockIdx.x * 256 + threadIdx.x;
  const int segi = gid >> 19;                   // 2^19 threads per input (4M elems / 8)
  const int e = (gid & 0x7FFFF) * 8;
  const float* s = (segi == 0) ? q : (segi == 1) ? k : v;
  unsigned short* dst = (segi == 0) ? dq : (segi == 1) ? dk : dv;
  const int m = e >> 10, kk = e & 1023;
  const int b = m >> 11, l = m & 2047;
  const float* sp = s + (size_t)((l << 1) + b) * HIDDIM + kk;
  const float4 f0 = *(const float4*)sp;
  const float4 f1 = *(const float4*)(sp + 4);
  *(uint4*)(dst + e) = pack8(f0, f1);
}

// rel_k [101][64] -> bf16 [112][64] zero-padded, AND rel_v -> transposed
// bf16 [64][128] (j>=101 zero). One dispatch, 60 blocks.
__global__ void cast_rel(const float* __restrict__ rk, const float* __restrict__ rv,
                         unsigned short* __restrict__ dk, unsigned short* __restrict__ dv) {
  const int e = blockIdx.x * 256 + threadIdx.x;
  if (e < 112 * 64) {
    dk[e] = (e < NREL * 64) ? f2bf(rk[e]) : (unsigned short)0;
  } else {
    const int e2 = e - 112 * 64;
    if (e2 >= 64 * 128) return;
    const int d = e2 >> 7, j = e2 & 127;
    dv[e2] = (j < NREL) ? f2bf(rv[j * DHD + d]) : (unsigned short)0;
  }
}

// ---------------------------------------------------------------------------
// Fused Q/K/V projection (verified R11). grid = 3*256; seg = bid>>8.
// 128x128 tile, BK=64, 4 waves (2x2) each 64x64. global_load_lds w16 staging,
// XOR bank swizzle on source col + ds_read addr (rule #21).
// ---------------------------------------------------------------------------
__global__ __launch_bounds__(256, 3) void gemm_qkv(
    const unsigned short* __restrict__ Xq, const unsigned short* __restrict__ Xk,
    const unsigned short* __restrict__ Xv, const unsigned short* __restrict__ Wcat,
    const float* __restrict__ bq, const float* __restrict__ bk, const float* __restrict__ bv,
    unsigned short* __restrict__ Qb, unsigned short* __restrict__ Kb,
    unsigned short* __restrict__ Vgt) {
  __shared__ __align__(16) unsigned short SH[17408];   // 34816 B (also Ct 128x136)
  unsigned short* LA = SH;           // [128][64] bf16, swizzled content
  unsigned short* LB = SH + 8192;

  const int tid = threadIdx.x;
  const int seg = blockIdx.x >> 8;
  const int t = blockIdx.x & 255;
  const int m0 = (t >> 3) * 128, n0 = (t & 7) * 128;

  const unsigned short* A = (seg == 0) ? Xq : (seg == 1) ? Xk : Xv;
  const unsigned short* W = Wcat + ((size_t)seg << 20);
  const float* bias = (seg == 0) ? bq : (seg == 1) ? bk : bv;

  const int lane = tid & 63, w = tid >> 6;
  const int c = lane & 15, quad = lane >> 4;

  const int srow = w * 32 + (lane >> 3);
  const int scol = ((lane & 7) ^ (lane >> 3)) << 3;    // elems
  const unsigned short* pA = A + (size_t)(m0 + srow) * 1024 + scol;
  const unsigned short* pW = W + (size_t)(n0 + srow) * 1024 + scol;
  unsigned short* lA = LA + w * 2048;
  unsigned short* lB = LB + w * 2048;

  const int wr = w >> 1, wc = w & 1;
  const int cx = (c & 7) << 3;                         // frag-read XOR (elems)

  f32x4 acc[4][4] = {};

  for (int k0 = 0; k0 < 1024; k0 += 64) {
#pragma unroll
    for (int i = 0; i < 4; i++) {
      gload16(pA + k0 + i * 8192, lA + i * 512);
      gload16(pW + k0 + i * 8192, lB + i * 512);
    }
    __syncthreads();   // drains vmcnt: staged data visible
#pragma unroll
    for (int ks = 0; ks < 2; ks++) {
      bf16x8 af[4], bfr[4];
#pragma unroll
      for (int f = 0; f < 4; f++) {
        af[f]  = *(const bf16x8*)&LA[(wr * 64 + f * 16 + c) * 64 + ((ks * 32 + quad * 8) ^ cx)];
        bfr[f] = *(const bf16x8*)&LB[(wc * 64 + f * 16 + c) * 64 + ((ks * 32 + quad * 8) ^ cx)];
      }
#pragma unroll
      for (int i = 0; i < 4; i++)
#pragma unroll
        for (int j = 0; j < 4; j++)
          acc[i][j] = MFMA(af[i], bfr[j], acc[i][j]);
    }
    __syncthreads();
  }

  const int b = m0 >> 11, l0 = m0 & 2047;
  const int h0 = n0 >> 6;
  if (seg < 2) {
    unsigned short* out = seg ? Kb : Qb;
#pragma unroll
    for (int i = 0; i < 4; i++)
#pragma unroll
      for (int j = 0; j < 4; j++) {
        const int nl = wc * 64 + j * 16 + c;            // C/D col = lane&15
        const float bv_ = bias[n0 + nl];
        const int h = h0 + (nl >> 6), d = nl & 63;
#pragma unroll
        for (int r = 0; r < 4; r++) {                   // C/D row = quad*4+r
          const int l = l0 + wr * 64 + i * 16 + quad * 4 + r;
          out[((size_t)((b * NH + h) * LSEQ + l) << 6) + d] = f2bf(acc[i][j][r] + bv_);
        }
      }
  } else {
    unsigned short* Ct = SH;
#pragma unroll
    for (int i = 0; i < 4; i++)
#pragma unroll
      for (int j = 0; j < 4; j++) {
        const int nl = wc * 64 + j * 16 + c;
        const float bv_ = bias[n0 + nl];
#pragma unroll
        for (int r = 0; r < 4; r++) {
          const int ml = wr * 64 + i * 16 + quad * 4 + r;
          Ct[nl * 136 + ml] = f2bf(acc[i][j][r] + bv_);
        }
      }
    __syncthreads();
    const int dr = tid >> 1, lc = (tid & 1) * 64;
    const int h = h0 + (dr >> 6), dd = dr & 63;
    unsigned short* dst = Vgt + ((size_t)((b * NH + h) * 64 + dd)) * LSEQ + l0 + lc;
    const unsigned short* src = Ct + dr * 136 + lc;
#pragma unroll
    for (int u = 0; u < 8; u++)
      *(uint4*)(dst + u * 8) = *(const uint4*)(src + u * 8);
  }
}

// ---------------------------------------------------------------------------
// Output GEMM: same proven 128^2 core, fp32 [L,B,HID] epilogue. grid = 256.
// Accumulation order identical to the old gemm64 -> bit-identical output.
// ---------------------------------------------------------------------------
__global__ __launch_bounds__(256, 3) void gemm_out(
    const unsigned short* __restrict__ A,    // [4096,1024] bf16 (attention out)
    const unsigned short* __restrict__ W,    // [1024,1024] bf16 (Wo)
    const float* __restrict__ bias,
    float* __restrict__ outF) {              // [L,B,HID] fp32
  __shared__ __align__(16) unsigned short SH[16384];
  unsigned short* LA = SH;
  unsigned short* LB = SH + 8192;

  const int tid = threadIdx.x;
  const int t = blockIdx.x;
  const int m0 = (t >> 3) * 128, n0 = (t & 7) * 128;

  const int lane = tid & 63, w = tid >> 6;
  const int c = lane & 15, quad = lane >> 4;

  const int srow = w * 32 + (lane >> 3);
  const int scol = ((lane & 7) ^ (lane >> 3)) << 3;
  const unsigned short* pA = A + (size_t)(m0 + srow) * 1024 + scol;
  const unsigned short* pW = W + (size_t)(n0 + srow) * 1024 + scol;
  unsigned short* lA = LA + w * 2048;
  unsigned short* lB = LB + w * 2048;

  const int wr = w >> 1, wc = w & 1;
  const int cx = (c & 7) << 3;

  f32x4 acc[4][4] = {};

  for (int k0 = 0; k0 < 1024; k0 += 64) {
#pragma unroll
    for (int i = 0; i < 4; i++) {
      gload16(pA + k0 + i * 8192, lA + i * 512);
      gload16(pW + k0 + i * 8192, lB + i * 512);
    }
    __syncthreads();
#pragma unroll
    for (int ks = 0; ks < 2; ks++) {
      bf16x8 af[4], bfr[4];
#pragma unroll
      for (int f = 0; f < 4; f++) {
        af[f]  = *(const bf16x8*)&LA[(wr * 64 + f * 16 + c) * 64 + ((ks * 32 + quad * 8) ^ cx)];
        bfr[f] = *(const bf16x8*)&LB[(wc * 64 + f * 16 + c) * 64 + ((ks * 32 + quad * 8) ^ cx)];
      }
#pragma unroll
      for (int i = 0; i < 4; i++)
#pragma unroll
        for (int j = 0; j < 4; j++)
          acc[i][j] = MFMA(af[i], bfr[j], acc[i][j]);
    }
    __syncthreads();
  }

  const int b = m0 >> 11, l0 = m0 & 2047;
#pragma unroll
  for (int i = 0; i < 4; i++)
#pragma unroll
    for (int j = 0; j < 4; j++) {
      const int n = n0 + wc * 64 + j * 16 + c;          // C/D col = lane&15
      const float bv_ = bias[n];
#pragma unroll
      for (int r = 0; r < 4; r++) {                     // C/D row = quad*4+r
        const int l = l0 + wr * 64 + i * 16 + quad * 4 + r;
        outF[(size_t)((l << 1) + b) * HIDDIM + n] = acc[i][j][r] + bv_;
      }
    }
}

// ---------------------------------------------------------------------------
// Hybrid flash attention (R12, byte-identical — best passing: 154.5us).
// R7 skeleton: block = one (b,h) x 64 q-rows, 4 waves x 16 q; K LDS
// double-buffered (KT=32, 1 barrier/iter); V global-direct.
// Swapped QK: lane(quad,c) owns q = qrow_w + c.
// LDS (u16): Kst 2x2304 @0 | Ptw 4x[16][40] @4608 | Tb 4x[16][104] @7168 |
//   SrS 4x[16][104] @13824  => 20480 u16 = 40960 B -> 4 blocks/CU.
// ---------------------------------------------------------------------------
#define KT 32
__global__ __launch_bounds__(256, 4) void attn_mfma(
    const unsigned short* __restrict__ Qb,   // [32][2048][64] bf16
    const unsigned short* __restrict__ Kb,   // [32][2048][64] bf16
    const unsigned short* __restrict__ Vgt,  // [32][64][2048] bf16 (V^T)
    const unsigned short* __restrict__ RKb,  // [112][64] bf16, zero-padded
    const unsigned short* __restrict__ RVb,  // [64][128] bf16 (rel_v^T), zero-padded
    unsigned short* __restrict__ outB) {     // [B*L][1024] bf16
  __shared__ __align__(16) unsigned short SH[20480];
  unsigned short* Kst = SH;                      // [2][32*72]

  const int tid = threadIdx.x;
  const int xcd = blockIdx.x & 7, slot = blockIdx.x >> 3;
  const int bh = (slot >> 5) * 8 + xcd;
  const int q0 = (slot & 31) * 64;

  const int lane = tid & 63, wq = tid >> 6;
  const int c = lane & 15, quad = lane >> 4;
  unsigned short* Ptw = SH + 4608 + wq * 640;    // [16][40] per wave
  unsigned short* Tb  = SH + 7168 + wq * 1664;   // [16][104] per wave
  unsigned short* SrS = SH + 13824 + wq * 1664;  // [16][104] per wave

  const size_t base = (size_t)bh * (LSEQ * DHD);
  const unsigned short* Qp = Qb + base;
  const unsigned short* Kp = Kb + base;
  const unsigned short* Vp = Vgt + base;

  const int qrow_w = q0 + wq * 16;    // wave's first global q

  // zero the whole Tb region (4 waves x 16x104 u16 = 13312 B)
  {
    uint4 z = {0u, 0u, 0u, 0u};
    uint4* tz = (uint4*)(SH + 7168);
    for (int e = tid; e < 832; e += 256) tz[e] = z;
  }

  // Q fragments (B-operand: n = lane&15 -> own q-row, k = quad*8+e -> d)
  const bf16x8 aq0 = *(const bf16x8*)&Qp[(size_t)(qrow_w + c) * DHD + quad * 8];
  const bf16x8 aq1 = *(const bf16x8*)&Qp[(size_t)(qrow_w + c) * DHD + 32 + quad * 8];

  // Sr swapped: lane(quad,c) -> Sr[j = jt*16+quad*4+r][q = qrow_w+c],
  // stored row-per-q: SrS[c][j] via cvt_pk u32 pairs (RNE, == f2bf bits)
#pragma unroll
  for (int jt = 0; jt < 7; jt++) {
    const bf16x8 rk0 = *(const bf16x8*)&RKb[(jt * 16 + c) * DHD + quad * 8];
    const bf16x8 rk1 = *(const bf16x8*)&RKb[(jt * 16 + c) * DHD + 32 + quad * 8];
    f32x4 s4 = {};
    s4 = MFMA(rk0, aq0, s4);
    s4 = MFMA(rk1, aq1, s4);
    const int jb = jt * 16 + quad * 4;
    const unsigned p01 = cvtpk(s4[0], s4[1]);
    const unsigned p23 = cvtpk(s4[2], s4[3]);
    if (jb <= 102)     *(unsigned*)&SrS[c * 104 + jb] = p01;
    if (jb + 2 <= 102) *(unsigned*)&SrS[c * 104 + jb + 2] = p23;
  }

  // prologue: stage K tile 0 into buf 0
  const int strow = tid >> 3, stcol = (tid & 7) * 8;
  {
    uint4 k0r = *(const uint4*)&Kp[(size_t)strow * DHD + stcol];
    *(uint4*)&Kst[strow * 72 + stcol] = k0r;
  }
  __syncthreads();   // covers Tb zero, SrS writes, K tile 0

  const float srvlo = bflo((unsigned)SrS[c * 104 + 0]);
  const float srvhi = bflo((unsigned)SrS[c * 104 + 100]);

  float lows = 0.f, highs = 0.f, mids = 0.f;
  f32x4 Od[4] = {};

  for (int it = 0; it < 64; ++it) {
    const int k0 = it * KT;
    const int cur = (it & 1) * 2304;
    // issue next K tile's global load + this tile's V frags up front
    uint4 kreg;
    if (it < 63) kreg = *(const uint4*)&Kp[(size_t)(k0 + KT + strow) * DHD + stcol];
    bf16x8 vf[4];
#pragma unroll
    for (int t = 0; t < 4; t++)
      vf[t] = *(const bf16x8*)&Vp[(size_t)(t * 16 + c) * LSEQ + k0 + quad * 8];

    // K frags from staged LDS (A-operand)
    const bf16x8 ka00 = *(const bf16x8*)&Kst[cur + c * 72 + quad * 8];
    const bf16x8 ka01 = *(const bf16x8*)&Kst[cur + c * 72 + 32 + quad * 8];
    const bf16x8 ka10 = *(const bf16x8*)&Kst[cur + (16 + c) * 72 + quad * 8];
    const bf16x8 ka11 = *(const bf16x8*)&Kst[cur + (16 + c) * 72 + 32 + quad * 8];
    f32x4 s0 = {}, s1 = {};
    s0 = MFMA(ka00, aq0, s0);
    s0 = MFMA(ka01, aq1, s0);
    s1 = MFMA(ka10, aq0, s1);
    s1 = MFMA(ka11, aq1, s1);

    // band mode (wave-uniform): 0 = all j==0, 2 = all j==100, 1 = mixed
    const int mode = (k0 + KT - 1 <= qrow_w - 50) ? 0 : (k0 >= qrow_w + 65) ? 2 : 1;

    unsigned pkA0, pkA1, pkB0, pkB1;
    if (mode != 1) {
      const float srv = (mode == 0) ? srvlo : srvhi;
      const float e0 = exp2f((s0[0] + srv) * SCL);
      const float e1 = exp2f((s0[1] + srv) * SCL);
      const float e2 = exp2f((s0[2] + srv) * SCL);
      const float e3 = exp2f((s0[3] + srv) * SCL);
      const float e4 = exp2f((s1[0] + srv) * SCL);
      const float e5 = exp2f((s1[1] + srv) * SCL);
      const float e6 = exp2f((s1[2] + srv) * SCL);
      const float e7 = exp2f((s1[3] + srv) * SCL);
      pkA0 = cvtpk(e0, e1); pkA1 = cvtpk(e2, e3);
      pkB0 = cvtpk(e4, e5); pkB1 = cvtpk(e6, e7);
      const float sq = ((pklo(pkA0) + pkhi(pkA0)) + (pklo(pkA1) + pkhi(pkA1)))
                     + ((pklo(pkB0) + pkhi(pkB0)) + (pklo(pkB1) + pkhi(pkB1)));
      if (mode == 0) lows += sq; else highs += sq;
    } else {
      const int kb0 = k0 + quad * 4 - (qrow_w + c) + 50;
      float ee[8]; int jj[8];
#pragma unroll
      for (int r = 0; r < 4; r++) {
        int j0 = kb0 + r;       j0 = j0 < 0 ? 0 : (j0 > 100 ? 100 : j0);
        int j1 = kb0 + 16 + r;  j1 = j1 < 0 ? 0 : (j1 > 100 ? 100 : j1);
        jj[r] = j0; jj[4 + r] = j1;
        const float sv0 = bflo((unsigned)SrS[c * 104 + j0]);
        const float sv1 = bflo((unsigned)SrS[c * 104 + j1]);
        ee[r]     = exp2f((s0[r] + sv0) * SCL);
        ee[4 + r] = exp2f((s1[r] + sv1) * SCL);
      }
      pkA0 = cvtpk(ee[0], ee[1]); pkA1 = cvtpk(ee[2], ee[3]);
      pkB0 = cvtpk(ee[4], ee[5]); pkB1 = cvtpk(ee[6], ee[7]);
      const unsigned pks[4] = {pkA0, pkA1, pkB0, pkB1};
#pragma unroll
      for (int i = 0; i < 4; i++) {
        const unsigned pk = pks[i];
        const float plo = pklo(pk), phi = pkhi(pk);
        const int jl = jj[2 * i], jh = jj[2 * i + 1];
        if (jl == 0) lows += plo;
        else if (jl == 100) highs += plo;
        else { mids += plo; Tb[c * 104 + jl] = (unsigned short)pk; }      // once
        if (jh == 0) lows += phi;
        else if (jh == 100) highs += phi;
        else { mids += phi; Tb[c * 104 + jh] = (unsigned short)(pk >> 16); }
      }
    }

    // P round-trip: 2x b64 write (row c, k-contiguous) + 1x b128 read (pitch 40)
    uint2 w0; w0.x = pkA0; w0.y = pkA1;
    uint2 w1; w1.x = pkB0; w1.y = pkB1;
    *(uint2*)&Ptw[c * 40 + quad * 4] = w0;
    *(uint2*)&Ptw[c * 40 + 16 + quad * 4] = w1;
    LDS_FENCE();   // cross-quad Ptw handoff (wave-internal)
    const bf16x8 ap = *(const bf16x8*)&Ptw[c * 40 + quad * 8];
#pragma unroll
    for (int t = 0; t < 4; t++)
      Od[t] = MFMA(ap, vf[t], Od[t]);

    // write next K tile into the other buffer; single barrier per iter
    if (it < 63) *(uint4*)&Kst[(cur ^ 2304) + strow * 72 + stcol] = kreg;
    __syncthreads();
  }

  // reduce per-q partials across the 4 quad-lanes holding the same c
#pragma unroll
  for (int m = 16; m < 64; m <<= 1) {
    lows  += __shfl_xor(lows,  m, 64);
    highs += __shfl_xor(highs, m, 64);
    mids  += __shfl_xor(mids,  m, 64);
  }
  const float rsum = (lows + highs) + mids;
  if (lane < 16) {
    Tb[c * 104 + 0]   = f2bf(lows);    // bucket 0 never stored in loop
    Tb[c * 104 + 100] = f2bf(highs);   // bucket 100 likewise
  }
  LDS_FENCE();   // Tb is per-wave: fence (not barrier) suffices

  // w2: O += T @ rel_v via MFMA; A-frag = b128 from own q-row (cols j>=101
  // are zero; kc==3 reads only quad==0 — cols 96..103 — rest contribute 0)
#pragma unroll
  for (int kc = 0; kc < 4; kc++) {
    uint4 zz = {0u, 0u, 0u, 0u};
    bf16x8 at = __builtin_bit_cast(bf16x8, zz);
    if (kc < 3 || quad == 0) at = *(const bf16x8*)&Tb[c * 104 + kc * 32 + quad * 8];
#pragma unroll
    for (int t = 0; t < 4; t++) {
      const bf16x8 bv = *(const bf16x8*)&RVb[(t * 16 + c) * 128 + kc * 32 + quad * 8];
      Od[t] = MFMA(at, bv, Od[t]);
    }
  }

  const int b = bh >> 4, h = bh & 15;
#pragma unroll
  for (int r = 0; r < 4; r++) {
    const float rs = __shfl(rsum, quad * 4 + r, 64);  // lane (quad*4+r) holds q-row quad*4+r
    const float inv = 1.f / rs;
    const int qg = qrow_w + quad * 4 + r;             // Od row = quad*4+r
    unsigned short* op = outB + (size_t)(b * LSEQ + qg) * HIDDIM + h * DHD + c;
#pragma unroll
    for (int t = 0; t < 4; t++) op[t * 16] = f2bf(Od[t][r] * inv);
  }
}

extern "C" void kernel_launch(void* const* d_in, const int* in_sizes, int n_in,
                              void* d_out, int out_size, void* d_ws, size_t ws_size,
                              hipStream_t stream) {
  const float* query = (const float*)d_in[0];
  const float* key   = (const float*)d_in[1];
  const float* value = (const float*)d_in[2];
  const float* Wq = (const float*)d_in[3];  const float* bq = (const float*)d_in[4];
  const float* Wk = (const float*)d_in[5];  const float* bk = (const float*)d_in[6];
  const float* Wv = (const float*)d_in[7];  const float* bv = (const float*)d_in[8];
  const float* Wo = (const float*)d_in[9];  const float* bo = (const float*)d_in[10];
  const float* relk = (const float*)d_in[11];
  const float* relv = (const float*)d_in[12];
  float* out = (float*)d_out;

  // 40 MB workspace layout
  char* w = (char*)d_ws;
  const size_t MB = 1ull << 20;
  unsigned short* Wcat = (unsigned short*)(w + 0 * MB);  // Wq,Wk,Wv,Wo at 0/2/4/6 MB
  unsigned short* Wob  = (unsigned short*)(w + 6 * MB);
  unsigned short* Xq   = (unsigned short*)(w + 8 * MB);  // 8 MB; reused as AOb
  unsigned short* Qb   = (unsigned short*)(w + 16 * MB); // [32][2048][64]
  unsigned short* Kb   = (unsigned short*)(w + 24 * MB);
  unsigned short* Vgt  = (unsigned short*)(w + 32 * MB); // [32][64][2048] (V^T)
  unsigned short* AOb  = Xq;
  unsigned short* RKb  = Wcat;                            // aliases Wq (dead post-QKV)
  unsigned short* RVb  = (unsigned short*)(w + 2 * MB);   // aliases Wk (dead post-QKV)
  // Xk/Xv scratch inside d_out (16 MB fp32, fully overwritten by final GEMM)
  unsigned short* Xk = (unsigned short*)out;
  unsigned short* Xv = (unsigned short*)out + (4u << 20);

  cast_w4<<<2048, 256, 0, stream>>>(Wq, Wk, Wv, Wo, Wcat);
  cast_x3<<<6144, 256, 0, stream>>>(query, key, value, Xq, Xk, Xv);
  gemm_qkv<<<768, 256, 0, stream>>>(Xq, Xk, Xv, Wcat, bq, bk, bv, Qb, Kb, Vgt);
  cast_rel<<<60, 256, 0, stream>>>(relk, relv, RKb, RVb);  // after QKV (aliases Wq/Wk)
  attn_mfma<<<1024, 256, 0, stream>>>(Qb, Kb, Vgt, RKb, RVb, AOb);
  gemm_out<<<256, 256, 0, stream>>>(AOb, Wob, bo, out);
}

// Round 10
// 325.059 us; speedup vs baseline: 1.3363x; 1.0027x over previous
//
#include <hip/hip_runtime.h>

// ---------------------------------------------------------------------------
// RelativeAttention: L=2048, B=2, HID=1024, H=16, DH=64, P=50
//   q,k,v = x @ W^T + b            (bf16 MFMA GEMM, fp32 accumulate)
//   attn  = softmax((QK^T + Sr_gather)/8),  Sr[q,j] = Q[q]·rel_k[j]
//   out_h = attn@V + T@rel_v,      T[q,j] = sum of p over bucket j
//   out   = out_h @ Wo^T + bo      (written [L,B,HID])
// R17 = R16 (attn byte-identical, 155.5us) + non-attn pool fixes:
//   - cast_wx: cast_w4 + cast_x3 merged into ONE dispatch (5 dispatches).
//   - gemm_qkv: Q/K epilogue converted from 64x2B scattered stores/thread to
//     the PROVEN LDS-transpose + 8x uint4 coalesced stores (same pattern as
//     the V^T segment, verified 3x). Bit-identical Q/K.
//   - gemm_out: retiled 128x128 -> 64x128 (grid 256 -> 512 = 2 blocks/CU,
//     LDS 24.6KB). Same per-element K-accumulation order -> bit-identical.
// ---------------------------------------------------------------------------

#define LSEQ 2048
#define HIDDIM 1024
#define NH 16
#define DHD 64
#define NREL 101
#define PMAX 50
#define SCL 0.18033688011112042f   // 0.125 * log2(e)

typedef __attribute__((ext_vector_type(8))) __bf16 bf16x8;
typedef __attribute__((ext_vector_type(4))) float f32x4;

#define MFMA(A, B, C) __builtin_amdgcn_mfma_f32_16x16x32_bf16(A, B, C, 0, 0, 0)
#define LDS_FENCE() asm volatile("s_waitcnt lgkmcnt(0)" ::: "memory")

__device__ __forceinline__ unsigned short f2bf(float f) {
  unsigned int u = __builtin_bit_cast(unsigned int, f);
  u += 0x7fffu + ((u >> 16) & 1u);   // RNE
  return (unsigned short)(u >> 16);
}
__device__ __forceinline__ float bflo(unsigned int u) { return __builtin_bit_cast(float, u << 16); }

__device__ __forceinline__ unsigned cvtpk(float lo, float hi) {
  unsigned r;
  asm("v_cvt_pk_bf16_f32 %0, %1, %2" : "=v"(r) : "v"(lo), "v"(hi));
  return r;
}
__device__ __forceinline__ float pklo(unsigned pk) { return __builtin_bit_cast(float, pk << 16); }
__device__ __forceinline__ float pkhi(unsigned pk) { return __builtin_bit_cast(float, pk & 0xffff0000u); }

__device__ __forceinline__ uint4 pack8(float4 f0, float4 f1) {
  uint4 o;
  o.x = (unsigned)f2bf(f0.x) | ((unsigned)f2bf(f0.y) << 16);
  o.y = (unsigned)f2bf(f0.z) | ((unsigned)f2bf(f0.w) << 16);
  o.z = (unsigned)f2bf(f1.x) | ((unsigned)f2bf(f1.y) << 16);
  o.w = (unsigned)f2bf(f1.z) | ((unsigned)f2bf(f1.w) << 16);
  return o;
}

// async global->LDS, 16B per lane, wave-uniform LDS base + lane*16
__device__ __forceinline__ void gload16(const unsigned short* g, unsigned short* l) {
  __builtin_amdgcn_global_load_lds(
      (const __attribute__((address_space(1))) unsigned int*)g,
      (__attribute__((address_space(3))) unsigned int*)l, 16, 0, 0);
}

// Merged cast: blocks [0,2048) cast 4 weights fp32->bf16 (Wcat);
// blocks [2048,8192) cast q/k/v [L,B,HID] fp32 -> bf16 [4096,1024].
__global__ void cast_wx(const float* __restrict__ w0, const float* __restrict__ w1,
                        const float* __restrict__ w2, const float* __restrict__ w3,
                        const float* __restrict__ xq, const float* __restrict__ xk,
                        const float* __restrict__ xv,
                        unsigned short* __restrict__ Wcat,
                        unsigned short* __restrict__ dq, unsigned short* __restrict__ dk,
                        unsigned short* __restrict__ dv) {
  const int bid = blockIdx.x;
  if (bid < 2048) {
    const int e = (bid * 256 + threadIdx.x) * 8;
    const int g = e >> 20;
    const float* s = (g == 0) ? w0 : (g == 1) ? w1 : (g == 2) ? w2 : w3;
    const int o = e & 0xFFFFF;
    const float4 f0 = *(const float4*)(s + o);
    const float4 f1 = *(const float4*)(s + o + 4);
    *(uint4*)(Wcat + e) = pack8(f0, f1);
  } else {
    const int gid = (bid - 2048) * 256 + threadIdx.x;
    const int segi = gid >> 19;                 // 2^19 threads per input
    const int e = (gid & 0x7FFFF) * 8;
    const float* s = (segi == 0) ? xq : (segi == 1) ? xk : xv;
    unsigned short* dst = (segi == 0) ? dq : (segi == 1) ? dk : dv;
    const int m = e >> 10, kk = e & 1023;
    const int b = m >> 11, l = m & 2047;
    const float* sp = s + (size_t)((l << 1) + b) * HIDDIM + kk;
    const float4 f0 = *(const float4*)sp;
    const float4 f1 = *(const float4*)(sp + 4);
    *(uint4*)(dst + e) = pack8(f0, f1);
  }
}

// rel_k [101][64] -> bf16 [112][64] zero-padded, AND rel_v -> transposed
// bf16 [64][128] (j>=101 zero). One dispatch, 60 blocks.
__global__ void cast_rel(const float* __restrict__ rk, const float* __restrict__ rv,
                         unsigned short* __restrict__ dk, unsigned short* __restrict__ dv) {
  const int e = blockIdx.x * 256 + threadIdx.x;
  if (e < 112 * 64) {
    dk[e] = (e < NREL * 64) ? f2bf(rk[e]) : (unsigned short)0;
  } else {
    const int e2 = e - 112 * 64;
    if (e2 >= 64 * 128) return;
    const int d = e2 >> 7, j = e2 & 127;
    dv[e2] = (j < NREL) ? f2bf(rv[j * DHD + d]) : (unsigned short)0;
  }
}

// ---------------------------------------------------------------------------
// Fused Q/K/V projection. grid = 3*256; seg = bid>>8.
// 128x128 tile, BK=64, 4 waves (2x2) each 64x64. global_load_lds w16 staging,
// XOR bank swizzle on source col + ds_read addr (rule #21).
// Epilogues: ALL segs now LDS-transpose + coalesced uint4 stores.
// ---------------------------------------------------------------------------
__global__ __launch_bounds__(256, 3) void gemm_qkv(
    const unsigned short* __restrict__ Xq, const unsigned short* __restrict__ Xk,
    const unsigned short* __restrict__ Xv, const unsigned short* __restrict__ Wcat,
    const float* __restrict__ bq, const float* __restrict__ bk, const float* __restrict__ bv,
    unsigned short* __restrict__ Qb, unsigned short* __restrict__ Kb,
    unsigned short* __restrict__ Vgt) {
  __shared__ __align__(16) unsigned short SH[17408];   // 34816 B (Ct 128x136 exact)
  unsigned short* LA = SH;           // [128][64] bf16, swizzled content
  unsigned short* LB = SH + 8192;

  const int tid = threadIdx.x;
  const int seg = blockIdx.x >> 8;
  const int t = blockIdx.x & 255;
  const int m0 = (t >> 3) * 128, n0 = (t & 7) * 128;

  const unsigned short* A = (seg == 0) ? Xq : (seg == 1) ? Xk : Xv;
  const unsigned short* W = Wcat + ((size_t)seg << 20);
  const float* bias = (seg == 0) ? bq : (seg == 1) ? bk : bv;

  const int lane = tid & 63, w = tid >> 6;
  const int c = lane & 15, quad = lane >> 4;

  const int srow = w * 32 + (lane >> 3);
  const int scol = ((lane & 7) ^ (lane >> 3)) << 3;    // elems
  const unsigned short* pA = A + (size_t)(m0 + srow) * 1024 + scol;
  const unsigned short* pW = W + (size_t)(n0 + srow) * 1024 + scol;
  unsigned short* lA = LA + w * 2048;
  unsigned short* lB = LB + w * 2048;

  const int wr = w >> 1, wc = w & 1;
  const int cx = (c & 7) << 3;                         // frag-read XOR (elems)

  f32x4 acc[4][4] = {};

  for (int k0 = 0; k0 < 1024; k0 += 64) {
#pragma unroll
    for (int i = 0; i < 4; i++) {
      gload16(pA + k0 + i * 8192, lA + i * 512);
      gload16(pW + k0 + i * 8192, lB + i * 512);
    }
    __syncthreads();   // drains vmcnt: staged data visible
#pragma unroll
    for (int ks = 0; ks < 2; ks++) {
      bf16x8 af[4], bfr[4];
#pragma unroll
      for (int f = 0; f < 4; f++) {
        af[f]  = *(const bf16x8*)&LA[(wr * 64 + f * 16 + c) * 64 + ((ks * 32 + quad * 8) ^ cx)];
        bfr[f] = *(const bf16x8*)&LB[(wc * 64 + f * 16 + c) * 64 + ((ks * 32 + quad * 8) ^ cx)];
      }
#pragma unroll
      for (int i = 0; i < 4; i++)
#pragma unroll
        for (int j = 0; j < 4; j++)
          acc[i][j] = MFMA(af[i], bfr[j], acc[i][j]);
    }
    __syncthreads();
  }

  const int b = m0 >> 11, l0 = m0 & 2047;
  const int h0 = n0 >> 6;
  if (seg < 2) {
    // Stage C as Ct[l_local][n_local] bf16 (pitch 136), then write head-rows
    // of 128B contiguous: thread -> (l_local = tid>>1, hh = tid&1).
    unsigned short* Ct = SH;
#pragma unroll
    for (int i = 0; i < 4; i++)
#pragma unroll
      for (int j = 0; j < 4; j++) {
        const int nl = wc * 64 + j * 16 + c;            // C/D col = lane&15
        const float bv_ = bias[n0 + nl];
#pragma unroll
        for (int r = 0; r < 4; r++) {                   // C/D row = quad*4+r
          const int ml = wr * 64 + i * 16 + quad * 4 + r;
          Ct[ml * 136 + nl] = f2bf(acc[i][j][r] + bv_);
        }
      }
    __syncthreads();
    unsigned short* out = seg ? Kb : Qb;
    const int ll = tid >> 1, hh = tid & 1;
    unsigned short* dst = out + ((size_t)((b * NH + h0 + hh) * LSEQ + l0 + ll)) * 64;
    const unsigned short* src = Ct + ll * 136 + hh * 64;
#pragma unroll
    for (int u = 0; u < 8; u++)
      *(uint4*)(dst + u * 8) = *(const uint4*)(src + u * 8);
  } else {
    unsigned short* Ct = SH;
#pragma unroll
    for (int i = 0; i < 4; i++)
#pragma unroll
      for (int j = 0; j < 4; j++) {
        const int nl = wc * 64 + j * 16 + c;
        const float bv_ = bias[n0 + nl];
#pragma unroll
        for (int r = 0; r < 4; r++) {
          const int ml = wr * 64 + i * 16 + quad * 4 + r;
          Ct[nl * 136 + ml] = f2bf(acc[i][j][r] + bv_);
        }
      }
    __syncthreads();
    const int dr = tid >> 1, lc = (tid & 1) * 64;
    const int h = h0 + (dr >> 6), dd = dr & 63;
    unsigned short* dst = Vgt + ((size_t)((b * NH + h) * 64 + dd)) * LSEQ + l0 + lc;
    const unsigned short* src = Ct + dr * 136 + lc;
#pragma unroll
    for (int u = 0; u < 8; u++)
      *(uint4*)(dst + u * 8) = *(const uint4*)(src + u * 8);
  }
}

// ---------------------------------------------------------------------------
// Output GEMM: 64x128 tile, grid 512 (2 blocks/CU), same proven staging core.
// 4 waves split N (each wave 64x32). Per-element K-accumulation order
// identical to previous versions -> bit-identical fp32 output.
// ---------------------------------------------------------------------------
__global__ __launch_bounds__(256, 2) void gemm_out(
    const unsigned short* __restrict__ A,    // [4096,1024] bf16 (attention out)
    const unsigned short* __restrict__ W,    // [1024,1024] bf16 (Wo)
    const float* __restrict__ bias,
    float* __restrict__ outF) {              // [L,B,HID] fp32
  __shared__ __align__(16) unsigned short SH[12288];   // LA 4096 + LB 8192 u16
  unsigned short* LA = SH;          // [64][64]
  unsigned short* LB = SH + 4096;   // [128][64]

  const int tid = threadIdx.x;
  const int t = blockIdx.x;
  const int m0 = (t >> 3) * 64, n0 = (t & 7) * 128;

  const int lane = tid & 63, w = tid >> 6;
  const int c = lane & 15, quad = lane >> 4;

  const int sr8 = lane >> 3;
  const int scol = ((lane & 7) ^ sr8) << 3;
  const unsigned short* pA = A + (size_t)(m0 + w * 16 + sr8) * 1024 + scol;
  const unsigned short* pW = W + (size_t)(n0 + w * 32 + sr8) * 1024 + scol;
  unsigned short* lA = LA + w * 1024;
  unsigned short* lB = LB + w * 2048;

  const int cx = (c & 7) << 3;

  f32x4 acc[4][2] = {};

  for (int k0 = 0; k0 < 1024; k0 += 64) {
#pragma unroll
    for (int i = 0; i < 2; i++)
      gload16(pA + k0 + i * 8192, lA + i * 512);
#pragma unroll
    for (int i = 0; i < 4; i++)
      gload16(pW + k0 + i * 8192, lB + i * 512);
    __syncthreads();
#pragma unroll
    for (int ks = 0; ks < 2; ks++) {
      bf16x8 af[4], bf2[2];
#pragma unroll
      for (int f = 0; f < 4; f++)
        af[f] = *(const bf16x8*)&LA[(f * 16 + c) * 64 + ((ks * 32 + quad * 8) ^ cx)];
#pragma unroll
      for (int f = 0; f < 2; f++)
        bf2[f] = *(const bf16x8*)&LB[(w * 32 + f * 16 + c) * 64 + ((ks * 32 + quad * 8) ^ cx)];
#pragma unroll
      for (int i = 0; i < 4; i++)
#pragma unroll
        for (int j = 0; j < 2; j++)
          acc[i][j] = MFMA(af[i], bf2[j], acc[i][j]);
    }
    __syncthreads();
  }

  const int b = m0 >> 11, l0 = m0 & 2047;
#pragma unroll
  for (int i = 0; i < 4; i++)
#pragma unroll
    for (int j = 0; j < 2; j++) {
      const int n = n0 + w * 32 + j * 16 + c;           // C/D col = lane&15
      const float bv_ = bias[n];
#pragma unroll
      for (int r = 0; r < 4; r++) {                     // C/D row = quad*4+r
        const int l = l0 + i * 16 + quad * 4 + r;
        outF[(size_t)((l << 1) + b) * HIDDIM + n] = acc[i][j][r] + bv_;
      }
    }
}

// ---------------------------------------------------------------------------
// Hybrid flash attention (R12/R16, byte-identical — best passing: 155.5us).
// R7 skeleton: block = one (b,h) x 64 q-rows, 4 waves x 16 q; K LDS
// double-buffered (KT=32, 1 barrier/iter); V global-direct.
// Swapped QK: lane(quad,c) owns q = qrow_w + c.
// LDS (u16): Kst 2x2304 @0 | Ptw 4x[16][40] @4608 | Tb 4x[16][104] @7168 |
//   SrS 4x[16][104] @13824  => 20480 u16 = 40960 B -> 4 blocks/CU.
// ---------------------------------------------------------------------------
#define KT 32
__global__ __launch_bounds__(256, 4) void attn_mfma(
    const unsigned short* __restrict__ Qb,   // [32][2048][64] bf16
    const unsigned short* __restrict__ Kb,   // [32][2048][64] bf16
    const unsigned short* __restrict__ Vgt,  // [32][64][2048] bf16 (V^T)
    const unsigned short* __restrict__ RKb,  // [112][64] bf16, zero-padded
    const unsigned short* __restrict__ RVb,  // [64][128] bf16 (rel_v^T), zero-padded
    unsigned short* __restrict__ outB) {     // [B*L][1024] bf16
  __shared__ __align__(16) unsigned short SH[20480];
  unsigned short* Kst = SH;                      // [2][32*72]

  const int tid = threadIdx.x;
  const int xcd = blockIdx.x & 7, slot = blockIdx.x >> 3;
  const int bh = (slot >> 5) * 8 + xcd;
  const int q0 = (slot & 31) * 64;

  const int lane = tid & 63, wq = tid >> 6;
  const int c = lane & 15, quad = lane >> 4;
  unsigned short* Ptw = SH + 4608 + wq * 640;    // [16][40] per wave
  unsigned short* Tb  = SH + 7168 + wq * 1664;   // [16][104] per wave
  unsigned short* SrS = SH + 13824 + wq * 1664;  // [16][104] per wave

  const size_t base = (size_t)bh * (LSEQ * DHD);
  const unsigned short* Qp = Qb + base;
  const unsigned short* Kp = Kb + base;
  const unsigned short* Vp = Vgt + base;

  const int qrow_w = q0 + wq * 16;    // wave's first global q

  // zero the whole Tb region (4 waves x 16x104 u16 = 13312 B)
  {
    uint4 z = {0u, 0u, 0u, 0u};
    uint4* tz = (uint4*)(SH + 7168);
    for (int e = tid; e < 832; e += 256) tz[e] = z;
  }

  // Q fragments (B-operand: n = lane&15 -> own q-row, k = quad*8+e -> d)
  const bf16x8 aq0 = *(const bf16x8*)&Qp[(size_t)(qrow_w + c) * DHD + quad * 8];
  const bf16x8 aq1 = *(const bf16x8*)&Qp[(size_t)(qrow_w + c) * DHD + 32 + quad * 8];

  // Sr swapped: lane(quad,c) -> Sr[j = jt*16+quad*4+r][q = qrow_w+c],
  // stored row-per-q: SrS[c][j] via cvt_pk u32 pairs (RNE, == f2bf bits)
#pragma unroll
  for (int jt = 0; jt < 7; jt++) {
    const bf16x8 rk0 = *(const bf16x8*)&RKb[(jt * 16 + c) * DHD + quad * 8];
    const bf16x8 rk1 = *(const bf16x8*)&RKb[(jt * 16 + c) * DHD + 32 + quad * 8];
    f32x4 s4 = {};
    s4 = MFMA(rk0, aq0, s4);
    s4 = MFMA(rk1, aq1, s4);
    const int jb = jt * 16 + quad * 4;
    const unsigned p01 = cvtpk(s4[0], s4[1]);
    const unsigned p23 = cvtpk(s4[2], s4[3]);
    if (jb <= 102)     *(unsigned*)&SrS[c * 104 + jb] = p01;
    if (jb + 2 <= 102) *(unsigned*)&SrS[c * 104 + jb + 2] = p23;
  }

  // prologue: stage K tile 0 into buf 0
  const int strow = tid >> 3, stcol = (tid & 7) * 8;
  {
    uint4 k0r = *(const uint4*)&Kp[(size_t)strow * DHD + stcol];
    *(uint4*)&Kst[strow * 72 + stcol] = k0r;
  }
  __syncthreads();   // covers Tb zero, SrS writes, K tile 0

  const float srvlo = bflo((unsigned)SrS[c * 104 + 0]);
  const float srvhi = bflo((unsigned)SrS[c * 104 + 100]);

  float lows = 0.f, highs = 0.f, mids = 0.f;
  f32x4 Od[4] = {};

  for (int it = 0; it < 64; ++it) {
    const int k0 = it * KT;
    const int cur = (it & 1) * 2304;
    // issue next K tile's global load + this tile's V frags up front
    uint4 kreg;
    if (it < 63) kreg = *(const uint4*)&Kp[(size_t)(k0 + KT + strow) * DHD + stcol];
    bf16x8 vf[4];
#pragma unroll
    for (int t = 0; t < 4; t++)
      vf[t] = *(const bf16x8*)&Vp[(size_t)(t * 16 + c) * LSEQ + k0 + quad * 8];

    // K frags from staged LDS (A-operand)
    const bf16x8 ka00 = *(const bf16x8*)&Kst[cur + c * 72 + quad * 8];
    const bf16x8 ka01 = *(const bf16x8*)&Kst[cur + c * 72 + 32 + quad * 8];
    const bf16x8 ka10 = *(const bf16x8*)&Kst[cur + (16 + c) * 72 + quad * 8];
    const bf16x8 ka11 = *(const bf16x8*)&Kst[cur + (16 + c) * 72 + 32 + quad * 8];
    f32x4 s0 = {}, s1 = {};
    s0 = MFMA(ka00, aq0, s0);
    s0 = MFMA(ka01, aq1, s0);
    s1 = MFMA(ka10, aq0, s1);
    s1 = MFMA(ka11, aq1, s1);

    // band mode (wave-uniform): 0 = all j==0, 2 = all j==100, 1 = mixed
    const int mode = (k0 + KT - 1 <= qrow_w - 50) ? 0 : (k0 >= qrow_w + 65) ? 2 : 1;

    unsigned pkA0, pkA1, pkB0, pkB1;
    if (mode != 1) {
      const float srv = (mode == 0) ? srvlo : srvhi;
      const float e0 = exp2f((s0[0] + srv) * SCL);
      const float e1 = exp2f((s0[1] + srv) * SCL);
      const float e2 = exp2f((s0[2] + srv) * SCL);
      const float e3 = exp2f((s0[3] + srv) * SCL);
      const float e4 = exp2f((s1[0] + srv) * SCL);
      const float e5 = exp2f((s1[1] + srv) * SCL);
      const float e6 = exp2f((s1[2] + srv) * SCL);
      const float e7 = exp2f((s1[3] + srv) * SCL);
      pkA0 = cvtpk(e0, e1); pkA1 = cvtpk(e2, e3);
      pkB0 = cvtpk(e4, e5); pkB1 = cvtpk(e6, e7);
      const float sq = ((pklo(pkA0) + pkhi(pkA0)) + (pklo(pkA1) + pkhi(pkA1)))
                     + ((pklo(pkB0) + pkhi(pkB0)) + (pklo(pkB1) + pkhi(pkB1)));
      if (mode == 0) lows += sq; else highs += sq;
    } else {
      const int kb0 = k0 + quad * 4 - (qrow_w + c) + 50;
      float ee[8]; int jj[8];
#pragma unroll
      for (int r = 0; r < 4; r++) {
        int j0 = kb0 + r;       j0 = j0 < 0 ? 0 : (j0 > 100 ? 100 : j0);
        int j1 = kb0 + 16 + r;  j1 = j1 < 0 ? 0 : (j1 > 100 ? 100 : j1);
        jj[r] = j0; jj[4 + r] = j1;
        const float sv0 = bflo((unsigned)SrS[c * 104 + j0]);
        const float sv1 = bflo((unsigned)SrS[c * 104 + j1]);
        ee[r]     = exp2f((s0[r] + sv0) * SCL);
        ee[4 + r] = exp2f((s1[r] + sv1) * SCL);
      }
      pkA0 = cvtpk(ee[0], ee[1]); pkA1 = cvtpk(ee[2], ee[3]);
      pkB0 = cvtpk(ee[4], ee[5]); pkB1 = cvtpk(ee[6], ee[7]);
      const unsigned pks[4] = {pkA0, pkA1, pkB0, pkB1};
#pragma unroll
      for (int i = 0; i < 4; i++) {
        const unsigned pk = pks[i];
        const float plo = pklo(pk), phi = pkhi(pk);
        const int jl = jj[2 * i], jh = jj[2 * i + 1];
        if (jl == 0) lows += plo;
        else if (jl == 100) highs += plo;
        else { mids += plo; Tb[c * 104 + jl] = (unsigned short)pk; }      // once
        if (jh == 0) lows += phi;
        else if (jh == 100) highs += phi;
        else { mids += phi; Tb[c * 104 + jh] = (unsigned short)(pk >> 16); }
      }
    }

    // P round-trip: 2x b64 write (row c, k-contiguous) + 1x b128 read (pitch 40)
    uint2 w0; w0.x = pkA0; w0.y = pkA1;
    uint2 w1; w1.x = pkB0; w1.y = pkB1;
    *(uint2*)&Ptw[c * 40 + quad * 4] = w0;
    *(uint2*)&Ptw[c * 40 + 16 + quad * 4] = w1;
    LDS_FENCE();   // cross-quad Ptw handoff (wave-internal)
    const bf16x8 ap = *(const bf16x8*)&Ptw[c * 40 + quad * 8];
#pragma unroll
    for (int t = 0; t < 4; t++)
      Od[t] = MFMA(ap, vf[t], Od[t]);

    // write next K tile into the other buffer; single barrier per iter
    if (it < 63) *(uint4*)&Kst[(cur ^ 2304) + strow * 72 + stcol] = kreg;
    __syncthreads();
  }

  // reduce per-q partials across the 4 quad-lanes holding the same c
#pragma unroll
  for (int m = 16; m < 64; m <<= 1) {
    lows  += __shfl_xor(lows,  m, 64);
    highs += __shfl_xor(highs, m, 64);
    mids  += __shfl_xor(mids,  m, 64);
  }
  const float rsum = (lows + highs) + mids;
  if (lane < 16) {
    Tb[c * 104 + 0]   = f2bf(lows);    // bucket 0 never stored in loop
    Tb[c * 104 + 100] = f2bf(highs);   // bucket 100 likewise
  }
  LDS_FENCE();   // Tb is per-wave: fence (not barrier) suffices

  // w2: O += T @ rel_v via MFMA; A-frag = b128 from own q-row (cols j>=101
  // are zero; kc==3 reads only quad==0 — cols 96..103 — rest contribute 0)
#pragma unroll
  for (int kc = 0; kc < 4; kc++) {
    uint4 zz = {0u, 0u, 0u, 0u};
    bf16x8 at = __builtin_bit_cast(bf16x8, zz);
    if (kc < 3 || quad == 0) at = *(const bf16x8*)&Tb[c * 104 + kc * 32 + quad * 8];
#pragma unroll
    for (int t = 0; t < 4; t++) {
      const bf16x8 bv = *(const bf16x8*)&RVb[(t * 16 + c) * 128 + kc * 32 + quad * 8];
      Od[t] = MFMA(at, bv, Od[t]);
    }
  }

  const int b = bh >> 4, h = bh & 15;
#pragma unroll
  for (int r = 0; r < 4; r++) {
    const float rs = __shfl(rsum, quad * 4 + r, 64);  // lane (quad*4+r) holds q-row quad*4+r
    const float inv = 1.f / rs;
    const int qg = qrow_w + quad * 4 + r;             // Od row = quad*4+r
    unsigned short* op = outB + (size_t)(b * LSEQ + qg) * HIDDIM + h * DHD + c;
#pragma unroll
    for (int t = 0; t < 4; t++) op[t * 16] = f2bf(Od[t][r] * inv);
  }
}

extern "C" void kernel_launch(void* const* d_in, const int* in_sizes, int n_in,
                              void* d_out, int out_size, void* d_ws, size_t ws_size,
                              hipStream_t stream) {
  const float* query = (const float*)d_in[0];
  const float* key   = (const float*)d_in[1];
  const float* value = (const float*)d_in[2];
  const float* Wq = (const float*)d_in[3];  const float* bq = (const float*)d_in[4];
  const float* Wk = (const float*)d_in[5];  const float* bk = (const float*)d_in[6];
  const float* Wv = (const float*)d_in[7];  const float* bv = (const float*)d_in[8];
  const float* Wo = (const float*)d_in[9];  const float* bo = (const float*)d_in[10];
  const float* relk = (const float*)d_in[11];
  const float* relv = (const float*)d_in[12];
  float* out = (float*)d_out;

  // 40 MB workspace layout
  char* w = (char*)d_ws;
  const size_t MB = 1ull << 20;
  unsigned short* Wcat = (unsigned short*)(w + 0 * MB);  // Wq,Wk,Wv,Wo at 0/2/4/6 MB
  unsigned short* Wob  = (unsigned short*)(w + 6 * MB);
  unsigned short* Xq   = (unsigned short*)(w + 8 * MB);  // 8 MB; reused as AOb
  unsigned short* Qb   = (unsigned short*)(w + 16 * MB); // [32][2048][64]
  unsigned short* Kb   = (unsigned short*)(w + 24 * MB);
  unsigned short* Vgt  = (unsigned short*)(w + 32 * MB); // [32][64][2048] (V^T)
  unsigned short* AOb  = Xq;
  unsigned short* RKb  = Wcat;                            // aliases Wq (dead post-QKV)
  unsigned short* RVb  = (unsigned short*)(w + 2 * MB);   // aliases Wk (dead post-QKV)
  // Xk/Xv scratch inside d_out (16 MB fp32, fully overwritten by final GEMM)
  unsigned short* Xk = (unsigned short*)out;
  unsigned short* Xv = (unsigned short*)out + (4u << 20);

  cast_wx<<<8192, 256, 0, stream>>>(Wq, Wk, Wv, Wo, query, key, value, Wcat, Xq, Xk, Xv);
  gemm_qkv<<<768, 256, 0, stream>>>(Xq, Xk, Xv, Wcat, bq, bk, bv, Qb, Kb, Vgt);
  cast_rel<<<60, 256, 0, stream>>>(relk, relv, RKb, RVb);  // after QKV (aliases Wq/Wk)
  attn_mfma<<<1024, 256, 0, stream>>>(Qb, Kb, Vgt, RKb, RVb, AOb);
  gemm_out<<<512, 256, 0, stream>>>(AOb, Wob, bo, out);
}